// Round 2
// baseline (4612.999 us; speedup 1.0000x reference)
//
#include <hip/hip_runtime.h>
#include <hip/hip_bf16.h>

// Problem constants: B=32, S=128, T=20 (19 dec steps), H=1024, D=512, K_attn=100, V=32000
// Inputs are float32 (per reference); output d_out is float32 (B,19,V).
// Strategy: convert weight matrices to bf16 once per call (workspace), run MFMA
// GEMMs in bf16 with fp32 accumulate; all state/biases/epilogues in fp32.

using bf16 = __hip_bfloat16;
typedef __attribute__((ext_vector_type(8))) __bf16 bf16x8;
typedef __attribute__((ext_vector_type(4))) float f32x4;

__device__ __forceinline__ bf16x8 ld8(const bf16* p) {
    return *reinterpret_cast<const bf16x8*>(p);
}
__device__ __forceinline__ float b2f(bf16 v) { return __bfloat162float(v); }
__device__ __forceinline__ bf16 f2b(float v) { return __float2bfloat16(v); }
__device__ __forceinline__ float sigf(float x) { return 1.0f / (1.0f + expf(-x)); }

#define MFMA(a, b, c) __builtin_amdgcn_mfma_f32_16x16x32_bf16((a), (b), (c), 0, 0, 0)

// ---------------------------------------------------------------------------
// f32 -> bf16 conversion for weight tensors. blockIdx.y selects tensor.
struct ConvDesc { const float* src; bf16* dst; int n; };
struct ConvTable { ConvDesc d[12]; };

__global__ __launch_bounds__(256) void k_conv(ConvTable tab) {
    ConvDesc cd = tab.d[blockIdx.y];
    int stride = gridDim.x * blockDim.x * 4;
    for (int i = (blockIdx.x * blockDim.x + threadIdx.x) * 4; i < cd.n; i += stride) {
        float4 v = *reinterpret_cast<const float4*>(cd.src + i);
        bf16 tmp[4] = {f2b(v.x), f2b(v.y), f2b(v.z), f2b(v.w)};
        *reinterpret_cast<ushort4*>(cd.dst + i) = *reinterpret_cast<const ushort4*>(tmp);
    }
}

// ---------------------------------------------------------------------------
// Gather bf16 embedding rows (512 bf16 = 256 u32 per row), one block per row.
__global__ __launch_bounds__(256) void k_gather(const unsigned int* __restrict__ table,
                                                const int* __restrict__ idx,
                                                unsigned int* __restrict__ out) {
    int r = blockIdx.x;
    out[(size_t)r * 256 + threadIdx.x] = table[(size_t)idx[r] * 256 + threadIdx.x];
}

// ---------------------------------------------------------------------------
// Generic big tiled GEMM: C = A(MxK) @ Bw(NxK)^T  (both row-major, bf16)
// 128x128 tile per block, 4 waves each 64x64 (4x4 of 16x16 MFMA tiles).
// mode 0: outF fp32 = C + bias
// mode 1: outF fp32 = tanh(C + bias)
// mode 2: logits fp32 at [((row&31)*19 + (row>>5))*32000 + n] = C + bias
// mode 3: outB bf16 = C (no bias)
__global__ __launch_bounds__(256) void k_gemm_bt(const bf16* __restrict__ A,
                                                 const bf16* __restrict__ Bw,
                                                 const float* __restrict__ bias,
                                                 float* __restrict__ outF,
                                                 bf16* __restrict__ outB,
                                                 int M, int N, int K, int ldo,
                                                 int ntN, int mode) {
    int bx = blockIdx.x;
    int mt = bx / ntN, nt = bx % ntN;
    int tid = threadIdx.x, wv = tid >> 6, l = tid & 63;
    int m0 = mt * 128 + (wv >> 1) * 64;
    int n0 = nt * 128 + (wv & 1) * 64;
    int r = l & 15, ko = (l >> 4) * 8;

    const bf16* ap[4];
    const bf16* bp[4];
#pragma unroll
    for (int i = 0; i < 4; ++i) {
        int row = m0 + i * 16 + r;
        if (row > M - 1) row = M - 1;
        ap[i] = A + (size_t)row * K + ko;
    }
#pragma unroll
    for (int j = 0; j < 4; ++j) {
        int n = n0 + j * 16 + r;
        if (n > N - 1) n = N - 1;
        bp[j] = Bw + (size_t)n * K + ko;
    }

    f32x4 zv = {0.f, 0.f, 0.f, 0.f};
    f32x4 acc[4][4];
#pragma unroll
    for (int i = 0; i < 4; ++i)
#pragma unroll
        for (int j = 0; j < 4; ++j) acc[i][j] = zv;

    int nk = K >> 5;
    for (int kk = 0; kk < nk; ++kk) {
        bf16x8 af[4], bfv[4];
#pragma unroll
        for (int i = 0; i < 4; ++i) af[i] = ld8(ap[i] + kk * 32);
#pragma unroll
        for (int j = 0; j < 4; ++j) bfv[j] = ld8(bp[j] + kk * 32);
#pragma unroll
        for (int i = 0; i < 4; ++i)
#pragma unroll
            for (int j = 0; j < 4; ++j) acc[i][j] = MFMA(af[i], bfv[j], acc[i][j]);
    }

    int ccol = l & 15, cr = (l >> 4) * 4;
#pragma unroll
    for (int i = 0; i < 4; ++i) {
#pragma unroll
        for (int j = 0; j < 4; ++j) {
            int n = n0 + j * 16 + ccol;
            if (n >= N) continue;
            float bv = bias ? bias[n] : 0.f;
#pragma unroll
            for (int q = 0; q < 4; ++q) {
                int row = m0 + i * 16 + cr + q;
                if (row >= M) continue;
                float v = acc[i][j][q] + bv;
                if (mode == 1) v = tanhf(v);
                if (mode == 2) {
                    outF[((size_t)(row & 31) * 19 + (size_t)(row >> 5)) * 32000 + n] = v;
                } else if (mode == 3) {
                    outB[(size_t)row * ldo + n] = f2b(v);
                } else {
                    outF[(size_t)row * ldo + n] = v;
                }
            }
        }
    }
}

// ---------------------------------------------------------------------------
// Small-M GEMM: one 16x16 tile per block (64 threads = 1 wave).
// C = A(MxK)@W(NxK)^T + bias ; act 0 none, 1 relu.
__global__ __launch_bounds__(64) void k_gemm_sm(const bf16* __restrict__ A,
                                                const bf16* __restrict__ W,
                                                const float* __restrict__ bias,
                                                float* __restrict__ outF, int ldof,
                                                bf16* __restrict__ outB, int ldob,
                                                int K, int ntN, int act) {
    int bx = blockIdx.x;
    int mt = bx / ntN, nt = bx % ntN;
    int l = threadIdx.x;
    int r = l & 15, ko = (l >> 4) * 8;
    const bf16* ap = A + (size_t)(mt * 16 + r) * K + ko;
    const bf16* bp = W + (size_t)(nt * 16 + r) * K + ko;
    f32x4 acc = {0.f, 0.f, 0.f, 0.f};
    int nk = K >> 5;
#pragma unroll 4
    for (int kk = 0; kk < nk; ++kk) acc = MFMA(ld8(ap + kk * 32), ld8(bp + kk * 32), acc);
    int n = nt * 16 + (l & 15);
    int cr = (l >> 4) * 4;
    float bv = bias ? bias[n] : 0.f;
#pragma unroll
    for (int q = 0; q < 4; ++q) {
        int row = mt * 16 + cr + q;
        float v = acc[q] + bv;
        if (act == 1) v = fmaxf(v, 0.f);
        if (outF) outF[(size_t)row * ldof + n] = v;
        if (outB) outB[(size_t)row * ldob + n] = f2b(v);
    }
}

// ---------------------------------------------------------------------------
// Encoder LSTM step. Grid 64 (j-blocks of 16), 256 thr = 4 waves = 4 gates.
__global__ __launch_bounds__(256) void k_enc_step(const bf16* __restrict__ Zx,
                                                  const bf16* __restrict__ Whh,
                                                  const float* __restrict__ bih,
                                                  const float* __restrict__ bhh,
                                                  const int* __restrict__ lens,
                                                  const bf16* __restrict__ hb_in,
                                                  bf16* __restrict__ hb_out,
                                                  float* __restrict__ h,
                                                  float* __restrict__ c,
                                                  bf16* __restrict__ cb16,
                                                  bf16* __restrict__ SH, int t) {
    __shared__ float zl[4][32][16];
    int j0 = blockIdx.x * 16;
    int tid = threadIdx.x;
    int g = tid >> 6, l = tid & 63;
    int r = l & 15, ko = (l >> 4) * 8;
    int n0 = g * 1024 + j0;

    const bf16* a0 = hb_in + (size_t)r * 1024 + ko;
    const bf16* a1 = hb_in + (size_t)(16 + r) * 1024 + ko;
    const bf16* bp = Whh + (size_t)(n0 + r) * 1024 + ko;
    f32x4 acc0 = {0.f, 0.f, 0.f, 0.f}, acc1 = {0.f, 0.f, 0.f, 0.f};
#pragma unroll 4
    for (int kk = 0; kk < 32; ++kk) {
        bf16x8 bv = ld8(bp + kk * 32);
        acc0 = MFMA(ld8(a0 + kk * 32), bv, acc0);
        acc1 = MFMA(ld8(a1 + kk * 32), bv, acc1);
    }
    int ccol = l & 15, cr = (l >> 4) * 4;
#pragma unroll
    for (int q = 0; q < 4; ++q) {
        zl[g][cr + q][ccol] = acc0[q];
        zl[g][16 + cr + q][ccol] = acc1[q];
    }
    __syncthreads();

    for (int e = tid; e < 512; e += 256) {
        int b = e >> 4, ji = e & 15;
        int j = j0 + ji;
        size_t zxi = ((size_t)(b * 128 + t)) * 4096 + j;
        float zi = zl[0][b][ji] + b2f(Zx[zxi])        + bih[j]        + bhh[j];
        float zf = zl[1][b][ji] + b2f(Zx[zxi + 1024]) + bih[1024 + j] + bhh[1024 + j];
        float zg = zl[2][b][ji] + b2f(Zx[zxi + 2048]) + bih[2048 + j] + bhh[2048 + j];
        float zo = zl[3][b][ji] + b2f(Zx[zxi + 3072]) + bih[3072 + j] + bhh[3072 + j];
        int hi = b * 1024 + j;
        float co = c[hi];
        float cn = sigf(zf) * co + sigf(zi) * tanhf(zg);
        float hn = sigf(zo) * tanhf(cn);
        bool msk = t < lens[b];
        float ho = h[hi];
        float hm = msk ? hn : ho;
        float cm = msk ? cn : co;
        h[hi] = hm;
        c[hi] = cm;
        hb_out[hi] = f2b(hm);
        cb16[hi] = f2b(cm);
        SH[((size_t)b * 128 + t) * 1024 + j] = msk ? f2b(hn) : f2b(0.f);
    }
}

// ---------------------------------------------------------------------------
// Decoder attention step (one block per batch element).
__global__ __launch_bounds__(256) void k_attn(const bf16* __restrict__ embedB,
                                              const int* __restrict__ trg,
                                              const float* __restrict__ akW,
                                              const float* __restrict__ akb,
                                              const float* __restrict__ qkB,
                                              const float* __restrict__ qvB,
                                              const int* __restrict__ lens,
                                              const float* __restrict__ hd,
                                              bf16* __restrict__ xin,
                                              bf16* __restrict__ featA, int t) {
    int b = blockIdx.x, tid = threadIdx.x;
    const unsigned int* er = (const unsigned int*)(embedB + (size_t)trg[b * 20 + t] * 512);
    ((unsigned int*)(xin + (size_t)b * 1536))[tid] = er[tid];

    __shared__ float ak[100];
    __shared__ float part[256];
    __shared__ float ew[128];
    __shared__ float mxs, inv_s;

    float s = 0.f;
    if (tid < 200) {
        int n = tid >> 1, hh = tid & 1;
        const float* wr = akW + (size_t)n * 1024 + hh * 512;
        const float* hr = hd + (size_t)b * 1024 + hh * 512;
#pragma unroll 8
        for (int k = 0; k < 512; ++k) s += hr[k] * wr[k];
    }
    part[tid] = s;
    __syncthreads();
    if (tid < 100) ak[tid] = tanhf(part[2 * tid] + part[2 * tid + 1] + akb[tid]);
    __syncthreads();

    if (tid < 128) {
        const float* qr = qkB + ((size_t)b * 128 + tid) * 100;
        float e = 0.f;
#pragma unroll 4
        for (int k = 0; k < 100; ++k) e += qr[k] * ak[k];
        ew[tid] = (tid < lens[b]) ? e : -INFINITY;
    }
    __syncthreads();
    if (tid == 0) {
        float m = ew[0];
        for (int s2 = 1; s2 < 128; ++s2) m = fmaxf(m, ew[s2]);
        mxs = m;
    }
    __syncthreads();
    if (tid < 128) ew[tid] = expf(ew[tid] - mxs);
    __syncthreads();
    if (tid == 0) {
        float sm = 0.f;
        for (int s2 = 0; s2 < 128; ++s2) sm += ew[s2];
        inv_s = 1.0f / sm;
    }
    __syncthreads();

    for (int j = tid; j < 1024; j += 256) {
        const float* qvb = qvB + ((size_t)b * 128) * 1024 + j;
        float a0 = 0.f;
#pragma unroll 4
        for (int s2 = 0; s2 < 128; ++s2) a0 += ew[s2] * qvb[(size_t)s2 * 1024];
        a0 *= inv_s;
        bf16 cb = f2b(a0);
        xin[(size_t)b * 1536 + 512 + j] = cb;
        featA[(size_t)b * 2048 + 1024 + j] = cb;
    }
}

// ---------------------------------------------------------------------------
// Decoder LSTM step.
__global__ __launch_bounds__(256) void k_dec_z(const bf16* __restrict__ xin,
                                               const bf16* __restrict__ Wih,
                                               const bf16* __restrict__ hb_in,
                                               const bf16* __restrict__ Whh,
                                               const float* __restrict__ bih,
                                               const float* __restrict__ bhh,
                                               float* __restrict__ hd,
                                               float* __restrict__ cd,
                                               bf16* __restrict__ hb_out,
                                               bf16* __restrict__ featA) {
    __shared__ float zl[4][32][16];
    int j0 = blockIdx.x * 16;
    int tid = threadIdx.x;
    int g = tid >> 6, l = tid & 63;
    int r = l & 15, ko = (l >> 4) * 8;
    int n0 = g * 1024 + j0;

    f32x4 acc0 = {0.f, 0.f, 0.f, 0.f}, acc1 = {0.f, 0.f, 0.f, 0.f};
    {
        const bf16* a0 = xin + (size_t)r * 1536 + ko;
        const bf16* a1 = xin + (size_t)(16 + r) * 1536 + ko;
        const bf16* bp = Wih + (size_t)(n0 + r) * 1536 + ko;
#pragma unroll 4
        for (int kk = 0; kk < 48; ++kk) {
            bf16x8 bv = ld8(bp + kk * 32);
            acc0 = MFMA(ld8(a0 + kk * 32), bv, acc0);
            acc1 = MFMA(ld8(a1 + kk * 32), bv, acc1);
        }
    }
    {
        const bf16* a0 = hb_in + (size_t)r * 1024 + ko;
        const bf16* a1 = hb_in + (size_t)(16 + r) * 1024 + ko;
        const bf16* bp = Whh + (size_t)(n0 + r) * 1024 + ko;
#pragma unroll 4
        for (int kk = 0; kk < 32; ++kk) {
            bf16x8 bv = ld8(bp + kk * 32);
            acc0 = MFMA(ld8(a0 + kk * 32), bv, acc0);
            acc1 = MFMA(ld8(a1 + kk * 32), bv, acc1);
        }
    }
    int ccol = l & 15, cr = (l >> 4) * 4;
#pragma unroll
    for (int q = 0; q < 4; ++q) {
        zl[g][cr + q][ccol] = acc0[q];
        zl[g][16 + cr + q][ccol] = acc1[q];
    }
    __syncthreads();

    for (int e = tid; e < 512; e += 256) {
        int b = e >> 4, ji = e & 15;
        int j = j0 + ji;
        float zi = zl[0][b][ji] + bih[j]        + bhh[j];
        float zf = zl[1][b][ji] + bih[1024 + j] + bhh[1024 + j];
        float zg = zl[2][b][ji] + bih[2048 + j] + bhh[2048 + j];
        float zo = zl[3][b][ji] + bih[3072 + j] + bhh[3072 + j];
        int hi = b * 1024 + j;
        float co = cd[hi];
        float cn = sigf(zf) * co + sigf(zi) * tanhf(zg);
        float hn = sigf(zo) * tanhf(cn);
        hd[hi] = hn;
        cd[hi] = cn;
        hb_out[hi] = f2b(hn);
        featA[(size_t)b * 2048 + j] = f2b(hn);
    }
}

// ---------------------------------------------------------------------------
extern "C" void kernel_launch(void* const* d_in, const int* in_sizes, int n_in,
                              void* d_out, int out_size, void* d_ws, size_t ws_size,
                              hipStream_t stream) {
    const float* embed   = (const float*)d_in[0];
    const float* enc_Wih = (const float*)d_in[1];
    const float* enc_Whh = (const float*)d_in[2];
    const float* enc_bih = (const float*)d_in[3];
    const float* enc_bhh = (const float*)d_in[4];
    const float* dec_Wih = (const float*)d_in[5];
    const float* dec_Whh = (const float*)d_in[6];
    const float* dec_bih = (const float*)d_in[7];
    const float* dec_bhh = (const float*)d_in[8];
    const float* qk_W    = (const float*)d_in[9];
    const float* qk_b    = (const float*)d_in[10];
    const float* qv_W    = (const float*)d_in[11];
    const float* qv_b    = (const float*)d_in[12];
    const float* ak_W    = (const float*)d_in[13];
    const float* ak_b    = (const float*)d_in[14];
    const float* out_W   = (const float*)d_in[15];
    const float* out_b   = (const float*)d_in[16];
    const float* wd_b    = (const float*)d_in[17];
    const float* hfc1_W  = (const float*)d_in[18];
    const float* hfc1_b  = (const float*)d_in[19];
    const float* hfc2_W  = (const float*)d_in[20];
    const float* hfc2_b  = (const float*)d_in[21];
    const float* cfc1_W  = (const float*)d_in[22];
    const float* cfc1_b  = (const float*)d_in[23];
    const float* cfc2_W  = (const float*)d_in[24];
    const float* cfc2_b  = (const float*)d_in[25];
    const int* src  = (const int*)d_in[26];
    const int* lens = (const int*)d_in[27];
    const int* trg  = (const int*)d_in[28];

    char* cur = (char*)d_ws;
    auto alloc = [&](size_t bytes) -> char* {
        char* p = cur;
        cur += (bytes + 255) & ~(size_t)255;
        return p;
    };
    bf16* embedB  = (bf16*)alloc((size_t)16384000 * 2);
    bf16* encWihB = (bf16*)alloc((size_t)2097152 * 2);
    bf16* encWhhB = (bf16*)alloc((size_t)4194304 * 2);
    bf16* decWihB = (bf16*)alloc((size_t)6291456 * 2);
    bf16* decWhhB = (bf16*)alloc((size_t)4194304 * 2);
    bf16* qkWB    = (bf16*)alloc((size_t)102400 * 2);
    bf16* qvWB    = (bf16*)alloc((size_t)1048576 * 2);
    bf16* outWB   = (bf16*)alloc((size_t)1048576 * 2);
    bf16* hfc1B   = (bf16*)alloc((size_t)2097152 * 2);
    bf16* hfc2B   = (bf16*)alloc((size_t)2097152 * 2);
    bf16* cfc1B   = (bf16*)alloc((size_t)2097152 * 2);
    bf16* cfc2B   = (bf16*)alloc((size_t)2097152 * 2);
    bf16*  Xsrc  = (bf16*)alloc((size_t)4096 * 512 * 2);
    bf16*  Zx    = (bf16*)alloc((size_t)4096 * 4096 * 2);
    bf16*  SH    = (bf16*)alloc((size_t)4096 * 1024 * 2);
    float* qkB   = (float*)alloc((size_t)4096 * 100 * 4);
    float* qvB   = (float*)alloc((size_t)4096 * 1024 * 4);
    float* h     = (float*)alloc(32 * 1024 * 4);
    float* c     = (float*)alloc(32 * 1024 * 4);
    bf16*  hbA   = (bf16*)alloc(32 * 1024 * 2);
    bf16*  hbB   = (bf16*)alloc(32 * 1024 * 2);
    bf16*  cbT   = (bf16*)alloc(32 * 1024 * 2);
    bf16*  t1    = (bf16*)alloc(32 * 2048 * 2);
    float* hd    = (float*)alloc(32 * 1024 * 4);
    float* cd    = (float*)alloc(32 * 1024 * 4);
    bf16*  hdA   = (bf16*)alloc(32 * 1024 * 2);
    bf16*  hdB   = (bf16*)alloc(32 * 1024 * 2);
    bf16*  xin   = (bf16*)alloc(32 * 1536 * 2);
    bf16*  featA = (bf16*)alloc(32 * 2048 * 2);
    bf16*  feats = (bf16*)alloc((size_t)608 * 512 * 2);
    if ((size_t)(cur - (char*)d_ws) > ws_size) return;  // workspace too small

    hipMemsetAsync(h, 0, 32 * 1024 * 4, stream);
    hipMemsetAsync(c, 0, 32 * 1024 * 4, stream);
    hipMemsetAsync(hbA, 0, 32 * 1024 * 2, stream);

    ConvTable tab;
    tab.d[0]  = {embed,   embedB,  16384000};
    tab.d[1]  = {enc_Wih, encWihB, 2097152};
    tab.d[2]  = {enc_Whh, encWhhB, 4194304};
    tab.d[3]  = {dec_Wih, decWihB, 6291456};
    tab.d[4]  = {dec_Whh, decWhhB, 4194304};
    tab.d[5]  = {qk_W,    qkWB,    102400};
    tab.d[6]  = {qv_W,    qvWB,    1048576};
    tab.d[7]  = {out_W,   outWB,   1048576};
    tab.d[8]  = {hfc1_W,  hfc1B,   2097152};
    tab.d[9]  = {hfc2_W,  hfc2B,   2097152};
    tab.d[10] = {cfc1_W,  cfc1B,   2097152};
    tab.d[11] = {cfc2_W,  cfc2B,   2097152};
    k_conv<<<dim3(1024, 12), 256, 0, stream>>>(tab);

    k_gather<<<4096, 256, 0, stream>>>((const unsigned int*)embedB, src, (unsigned int*)Xsrc);

    k_gemm_bt<<<32 * 32, 256, 0, stream>>>(Xsrc, encWihB, nullptr, nullptr, Zx,
                                           4096, 4096, 512, 4096, 32, 3);

    for (int t = 0; t < 128; ++t) {
        const bf16* hin = (t & 1) ? hbB : hbA;
        bf16* hout = (t & 1) ? hbA : hbB;
        k_enc_step<<<64, 256, 0, stream>>>(Zx, encWhhB, enc_bih, enc_bhh, lens,
                                           hin, hout, h, c, cbT, SH, t);
    }
    bf16* hbT = hbA;  // output buffer of step t=127

    k_gemm_sm<<<256, 64, 0, stream>>>(hbT, hfc1B, hfc1_b, nullptr, 0, t1, 2048, 1024, 128, 1);
    k_gemm_sm<<<128, 64, 0, stream>>>(t1, hfc2B, hfc2_b, hd, 1024, hdA, 1024, 2048, 64, 0);
    k_gemm_sm<<<256, 64, 0, stream>>>(cbT, cfc1B, cfc1_b, nullptr, 0, t1, 2048, 1024, 128, 1);
    k_gemm_sm<<<128, 64, 0, stream>>>(t1, cfc2B, cfc2_b, cd, 1024, nullptr, 0, 2048, 64, 0);

    k_gemm_bt<<<32, 256, 0, stream>>>(SH, qkWB, qk_b, qkB, nullptr,
                                      4096, 100, 1024, 100, 1, 1);
    k_gemm_bt<<<256, 256, 0, stream>>>(SH, qvWB, qv_b, qvB, nullptr,
                                       4096, 1024, 1024, 1024, 8, 0);

    for (int t = 0; t < 19; ++t) {
        const bf16* hin = (t & 1) ? hdB : hdA;
        bf16* hout = (t & 1) ? hdA : hdB;
        k_attn<<<32, 256, 0, stream>>>(embedB, trg, ak_W, ak_b, qkB, qvB, lens, hd,
                                       xin, featA, t);
        k_dec_z<<<64, 256, 0, stream>>>(xin, decWihB, hin, decWhhB, dec_bih, dec_bhh,
                                        hd, cd, hout, featA);
        k_gemm_sm<<<64, 64, 0, stream>>>(featA, outWB, out_b, nullptr, 0,
                                         feats + (size_t)t * 32 * 512, 512, 2048, 32, 0);
    }

    k_gemm_bt<<<5 * 250, 256, 0, stream>>>(feats, embedB, wd_b, (float*)d_out, nullptr,
                                           608, 32000, 512, 0, 250, 2);
}